// Round 11
// baseline (1312.935 us; speedup 1.0000x reference)
//
#include <hip/hip_runtime.h>
#include <hip/hip_bf16.h>
#include <math.h>

// Problem constants
#define BATCH 16384
#define DIN   480
#define DH    512
#define DOUT  360
#define NEXP  8
#define GIN   64
#define GH    128
#define KP    512          // padded K for all expert layers

typedef short bf16x8 __attribute__((ext_vector_type(8)));
typedef float f32x4  __attribute__((ext_vector_type(4)));

__device__ __forceinline__ short f2bf(float f) {
    __hip_bfloat16 h = __float2bfloat16(f);
    return *reinterpret_cast<short*>(&h);
}
__device__ __forceinline__ float eluf(float x) { return x > 0.f ? x : expf(x) - 1.f; }

__device__ __forceinline__ void gll16(const void* g, void* l) {
    __builtin_amdgcn_global_load_lds(
        (const __attribute__((address_space(1))) unsigned int*)g,
        (__attribute__((address_space(3))) unsigned int*)l, 16, 0, 0);
}

// ---------------------------------------------------------------------------
// Kernel 1: xn = (x - mu) / sigma -> bf16, pitch 512 (cols 480..511 zero).
// ---------------------------------------------------------------------------
__global__ void prep_xn_kernel(const float* __restrict__ x,
                               const float* __restrict__ Xnorm,
                               short* __restrict__ xnbf) {
    const int tid = blockIdx.x * 256 + threadIdx.x;
    const int row = tid >> 6;
    const int c   = (tid & 63) * 8;
    short v8[8];
    if (c < DIN) {
        #pragma unroll
        for (int j = 0; j < 8; ++j) {
            float v = (x[(size_t)row * DIN + c + j] - Xnorm[c + j]) / Xnorm[DIN + c + j];
            v8[j] = f2bf(v);
        }
    } else {
        #pragma unroll
        for (int j = 0; j < 8; ++j) v8[j] = 0;
    }
    *(uint4*)&xnbf[(size_t)row * KP + c] = *(uint4*)v8;
}

// ---------------------------------------------------------------------------
// Kernel 2: transpose + convert W (E,K,N) f32 -> Wt (E,NPAD,KP) bf16, zero pad.
// ---------------------------------------------------------------------------
__global__ void transpose_w_kernel(const float* __restrict__ src,
                                   short* __restrict__ dst,
                                   int K, int N, int NPAD) {
    __shared__ float tile[32][33];
    const int ntn = NPAD / 32;
    const int ntk = KP / 32;
    int lin = blockIdx.x;
    const int e  = lin / (ntk * ntn);
    lin -= e * ntk * ntn;
    const int kt = lin / ntn;
    const int nt = lin % ntn;
    const int t = threadIdx.x;
    #pragma unroll
    for (int r = 0; r < 4; ++r) {
        int idx = t + r * 256;
        int i = idx >> 5;          // k within tile
        int j = idx & 31;          // n within tile
        int k = kt * 32 + i;
        int n = nt * 32 + j;
        float v = (n < N && k < K) ? src[((size_t)e * K + k) * N + n] : 0.f;
        tile[i][j] = v;
    }
    __syncthreads();
    #pragma unroll
    for (int r = 0; r < 4; ++r) {
        int idx = t + r * 256;
        int i2 = idx & 31;         // k (contiguous on write)
        int j2 = idx >> 5;         // n
        dst[((size_t)e * NPAD + nt * 32 + j2) * KP + kt * 32 + i2] = f2bf(tile[i2][j2]);
    }
}

// ---------------------------------------------------------------------------
// Kernel 3: gating MLP -> softmax weights w[B][8] (fp32).
// ---------------------------------------------------------------------------
__global__ __launch_bounds__(256) void gating_kernel(
    const float* __restrict__ x, const float* __restrict__ Xnorm,
    const float* __restrict__ G1W, const float* __restrict__ G1b,
    const float* __restrict__ G2W, const float* __restrict__ G2b,
    const float* __restrict__ G3W, const float* __restrict__ G3b,
    const int* __restrict__ gidx, float* __restrict__ wout) {

    __shared__ float g2s[GH * GH];
    __shared__ float g3s[GH * NEXP];
    __shared__ float b1s[GH], b2s[GH], b3s[NEXP];
    __shared__ float g0b[4][GIN], h1b[4][GH], h2b[4][GH];

    const int t = threadIdx.x;
    const int lane = t & 63;
    const int wid  = t >> 6;

    for (int i = t; i < GH * GH; i += 256) g2s[i] = G2W[i];
    for (int i = t; i < GH * NEXP; i += 256) g3s[i] = G3W[i];
    if (t < GH) { b1s[t] = G1b[t]; b2s[t] = G2b[t]; }
    if (t < NEXP) b3s[t] = G3b[t];
    __syncthreads();

    const int gi = gidx[lane];
    const float mu = Xnorm[gi];
    const float inv_sig = 1.f / Xnorm[DIN + gi];

    for (int it = 0; it < 16; ++it) {
        const int row = (blockIdx.x * 4 + wid) * 16 + it;
        float g0 = (x[(size_t)row * DIN + gi] - mu) * inv_sig;
        g0b[wid][lane] = g0;
        __syncthreads();
        float h1a = b1s[lane], h1c = b1s[lane + 64];
        #pragma unroll 8
        for (int i = 0; i < GIN; ++i) {
            float g = g0b[wid][i];
            h1a += g * G1W[i * GH + lane];
            h1c += g * G1W[i * GH + lane + 64];
        }
        h1b[wid][lane] = eluf(h1a);
        h1b[wid][lane + 64] = eluf(h1c);
        __syncthreads();
        float h2a = b2s[lane], h2c = b2s[lane + 64];
        #pragma unroll 8
        for (int i = 0; i < GH; ++i) {
            float h = h1b[wid][i];
            h2a += h * g2s[i * GH + lane];
            h2c += h * g2s[i * GH + lane + 64];
        }
        h2b[wid][lane] = eluf(h2a);
        h2b[wid][lane + 64] = eluf(h2c);
        __syncthreads();
        const int e  = lane & 7;
        const int ch = lane >> 3;
        float p = 0.f;
        #pragma unroll
        for (int i2 = 0; i2 < 16; ++i2) {
            int i = ch * 16 + i2;
            p += h2b[wid][i] * g3s[i * NEXP + e];
        }
        p += __shfl_xor(p, 8);
        p += __shfl_xor(p, 16);
        p += __shfl_xor(p, 32);
        p += b3s[e];
        float mx = p;
        mx = fmaxf(mx, __shfl_xor(mx, 1));
        mx = fmaxf(mx, __shfl_xor(mx, 2));
        mx = fmaxf(mx, __shfl_xor(mx, 4));
        float ex = expf(p - mx);
        float sm = ex;
        sm += __shfl_xor(sm, 1);
        sm += __shfl_xor(sm, 2);
        sm += __shfl_xor(sm, 4);
        float wv = ex / sm;
        if (lane < NEXP) wout[(size_t)row * NEXP + lane] = wv;
        __syncthreads();
    }
}

// ---------------------------------------------------------------------------
// Kernel 4 v11: v8 dataflow (A in LDS once per kt, B triple-buffered LDS,
// 2-deep gll prefetch, same FIFO-audited vmcnt rotation) + one-step B-frag
// register lookahead (m201 pattern) + __launch_bounds__(512,1) so the
// allocator has the full 256-VGPR budget (the (512,2) builds were capped at
// 128 and spilled on every lookahead attempt).
// Step s: issue B(s+2) [A at e==6] -> 32 MFMA on bcU (regs from last step,
// zero lgkm stall) -> vmcnt(2/6/0) -> barrier -> ds_read B(s+1)->bcF -> mix
// (covers ds_read latency) -> swap. One barrier per step; bcF crosses
// exactly one barrier.
// ---------------------------------------------------------------------------
#define ESTEP(EVAL, BCU, BCF)                                                  \
{                                                                              \
    const int e_ = (EVAL);                                                     \
    const int s_ = kt * 8 + e_;                                                \
    const int kB1 = (kB == 2) ? 0 : kB + 1;                                    \
    const int kB2 = (kB1 == 2) ? 0 : kB1 + 1;                                  \
    /* a) issue prefetches */                                                  \
    if (s_ < 62) {                                                             \
        const int s2 = s_ + 2;                                                 \
        const size_t ob = (size_t)(s2 & 7) * NPAD * KP + (size_t)(s2 >> 3) * 64; \
        _Pragma("unroll")                                                      \
        for (int i = 0; i < 2; ++i)                                            \
            gll16(baseB[i] + ob, bufB0 + kB2 * (128 * 64) + (wid * 2 + i) * 512); \
    }                                                                          \
    if (e_ == 6 && kt < 7) {                                                   \
        const size_t oa = (size_t)(kt + 1) * 64;                               \
        _Pragma("unroll")                                                      \
        for (int i = 0; i < 4; ++i)                                            \
            gll16(baseA[i] + oa,                                               \
                  bufA0 + ((kt + 1) & 1) * (256 * 64) + (wid * 4 + i) * 512);  \
    }                                                                          \
    /* b) MFMA on register fragments (loaded during previous step) */          \
    f32x4 acc[4][4];                                                           \
    __builtin_amdgcn_s_setprio(1);                                             \
    _Pragma("unroll")                                                          \
    for (int mi = 0; mi < 4; ++mi)                                             \
        _Pragma("unroll")                                                      \
        for (int ni = 0; ni < 4; ++ni)                                         \
            acc[mi][ni] = __builtin_amdgcn_mfma_f32_16x16x32_bf16(             \
                af0[mi], BCU[ni], zf, 0, 0, 0);                                \
    __builtin_amdgcn_s_setprio(0);                                             \
    __builtin_amdgcn_s_setprio(1);                                             \
    _Pragma("unroll")                                                          \
    for (int mi = 0; mi < 4; ++mi)                                             \
        _Pragma("unroll")                                                      \
        for (int ni = 0; ni < 4; ++ni)                                         \
            acc[mi][ni] = __builtin_amdgcn_mfma_f32_16x16x32_bf16(             \
                af1[mi], BCU[4 + ni], acc[mi][ni], 0, 0, 0);                   \
    __builtin_amdgcn_s_setprio(0);                                             \
    /* c) counted wait + publish barrier (drains loads issued >= 1 step ago) */\
    if (kt == 7 && e_ >= 6)     asm volatile("s_waitcnt vmcnt(0)" ::: "memory"); \
    else if (e_ == 6)           asm volatile("s_waitcnt vmcnt(6)" ::: "memory"); \
    else                        asm volatile("s_waitcnt vmcnt(2)" ::: "memory"); \
    asm volatile("s_barrier" ::: "memory");                                    \
    /* d) lookahead: ds_read B(s+1) fragments into the fill buffer */          \
    if (s_ < 63) {                                                             \
        const short* Bn = bufB0 + kB1 * (128 * 64);                            \
        _Pragma("unroll")                                                      \
        for (int ni = 0; ni < 4; ++ni) {                                       \
            BCF[ni]     = *(const bf16x8*)(Bn + brow + ni * 1024 + xo0);       \
            BCF[4 + ni] = *(const bf16x8*)(Bn + brow + ni * 1024 + xo1);       \
        }                                                                      \
    }                                                                          \
    /* e) mix (VALU; covers the ds_read latency) */                            \
    {                                                                          \
        f32x4 wv[4];                                                           \
        _Pragma("unroll")                                                      \
        for (int mi = 0; mi < 4; ++mi)                                         \
            wv[mi] = *(const f32x4*)&wlsT[e_][wr * 64 + mi * 16 + l4 * 4];     \
        _Pragma("unroll")                                                      \
        for (int mi = 0; mi < 4; ++mi)                                         \
            _Pragma("unroll")                                                  \
            for (int ni = 0; ni < 4; ++ni)                                     \
                _Pragma("unroll")                                              \
                for (int j = 0; j < 4; ++j)                                    \
                    accF[mi][ni][j] += wv[mi][j] * acc[mi][ni][j];             \
    }                                                                          \
    kB = kB1;                                                                  \
}

template<int NPAD, int NREAL, int MODE>
__global__ __launch_bounds__(512, 1) void expert_v11_kernel(
    const short* __restrict__ A, const short* __restrict__ Wt,
    const float* __restrict__ wgate, const float* __restrict__ bias,
    const float* __restrict__ Ynorm, void* __restrict__ Out) {

    __shared__ __align__(16) short bufA[2][256 * 64];   // 64 KB
    __shared__ __align__(16) short bufB[3][128 * 64];   // 48 KB
    __shared__ float wlsT[NEXP][256];                   // 8 KB

    const int t = threadIdx.x;
    const int lane = t & 63;
    const int wid  = t >> 6;          // 0..7
    const int wr = wid >> 1;          // 0..3 : 64-row strip
    const int wc = wid & 1;           // 0..1 : 64-col strip
    const int l4 = lane >> 4, lr = lane & 15;

    // XCD-chunked block swizzle (grid % 8 == 0 for all layers)
    constexpr int NN = NPAD / 128;
    constexpr int nwg = (BATCH / 256) * NN;
    constexpr int cpx = nwg / 8;
    const int lb  = (blockIdx.x & 7) * cpx + (blockIdx.x >> 3);
    const int m0  = (lb / NN) * 256;
    const int n0  = (lb % NN) * 128;

    // gating weights transposed: wlsT[e][row] = wgate[(m0+row)*8+e]
    for (int i = t; i < NEXP * 256; i += 512) {
        int e = i >> 8, r = i & 255;
        wlsT[e][r] = wgate[(size_t)(m0 + r) * NEXP + e];
    }

    // staging geometry: 16B chunk per lane; 8-row x 8-slot groups, XOR swizzle
    const int srow  = lane >> 3;              // 0..7
    const int sslot = (lane & 7) ^ srow;      // pre-swizzled source 16B-slot

    const short* baseA[4];
    #pragma unroll
    for (int i = 0; i < 4; ++i)
        baseA[i] = A + (size_t)(m0 + (wid * 4 + i) * 8 + srow) * KP + sslot * 8;
    const short* baseB[2];
    #pragma unroll
    for (int i = 0; i < 2; ++i)
        baseB[i] = Wt + (size_t)(n0 + (wid * 2 + i) * 8 + srow) * KP + sslot * 8;

    short* const bufA0 = &bufA[0][0];
    short* const bufB0 = &bufB[0][0];

    f32x4 accF[4][4];
    #pragma unroll
    for (int mi = 0; mi < 4; ++mi)
        #pragma unroll
        for (int ni = 0; ni < 4; ++ni)
            accF[mi][ni] = (f32x4){0.f, 0.f, 0.f, 0.f};
    const f32x4 zf = (f32x4){0.f, 0.f, 0.f, 0.f};

    // prologue: A(kt=0) -> bufA[0]; B(s=0) -> bufB[0]; B(s=1) -> bufB[1]; drain.
    #pragma unroll
    for (int i = 0; i < 4; ++i)
        gll16(baseA[i], bufA0 + (wid * 4 + i) * 512);
    #pragma unroll
    for (int i = 0; i < 2; ++i)
        gll16(baseB[i], bufB0 + (wid * 2 + i) * 512);
    #pragma unroll
    for (int i = 0; i < 2; ++i)
        gll16(baseB[i] + (size_t)NPAD * KP, bufB0 + 128 * 64 + (wid * 2 + i) * 512);
    __syncthreads();

    const int xo0 = (l4 * 8) ^ ((lr & 7) << 3);
    const int xo1 = (32 + l4 * 8) ^ ((lr & 7) << 3);
    const int arow = (wr * 64 + lr) * 64;      // af row base (mi adds 16*64)
    const int brow = (wc * 64 + lr) * 64;      // b  row base (ni adds 16*64)

    // initial register fragments: B(0) from slot 0
    bf16x8 bcA[8], bcB[8];
    #pragma unroll
    for (int ni = 0; ni < 4; ++ni) {
        bcA[ni]     = *(const bf16x8*)(bufB0 + brow + ni * 1024 + xo0);
        bcA[4 + ni] = *(const bf16x8*)(bufB0 + brow + ni * 1024 + xo1);
    }

    int kB = 0;                                    // s % 3
    #pragma unroll 1
    for (int kt = 0; kt < 8; ++kt) {
        const short* Ab = bufA0 + (kt & 1) * (256 * 64);

        // hoisted A fragments: valid for all 8 e-steps of this kt
        bf16x8 af0[4], af1[4];
        #pragma unroll
        for (int mi = 0; mi < 4; ++mi) {
            af0[mi] = *(const bf16x8*)(Ab + arow + mi * 1024 + xo0);
            af1[mi] = *(const bf16x8*)(Ab + arow + mi * 1024 + xo1);
        }

        #pragma unroll 1
        for (int ee = 0; ee < 4; ++ee) {
            ESTEP(2 * ee,     bcA, bcB)
            ESTEP(2 * ee + 1, bcB, bcA)
        }
    }

    // epilogue: rank-1 bias term  accF += sum_e w_e[row] * bias_e[col]
    {
        float bv[4][NEXP];
        #pragma unroll
        for (int ni = 0; ni < 4; ++ni) {
            int ng = n0 + wc * 64 + ni * 16 + lr;
            #pragma unroll
            for (int e = 0; e < NEXP; ++e)
                bv[ni][e] = (ng < NREAL) ? bias[(size_t)e * NREAL + ng] : 0.f;
        }
        #pragma unroll
        for (int mi = 0; mi < 4; ++mi) {
            f32x4 wve[NEXP];
            #pragma unroll
            for (int e = 0; e < NEXP; ++e)
                wve[e] = *(const f32x4*)&wlsT[e][wr * 64 + mi * 16 + l4 * 4];
            #pragma unroll
            for (int ni = 0; ni < 4; ++ni)
                #pragma unroll
                for (int j = 0; j < 4; ++j) {
                    float sum = 0.f;
                    #pragma unroll
                    for (int e = 0; e < NEXP; ++e) sum += wve[e][j] * bv[ni][e];
                    accF[mi][ni][j] += sum;
                }
        }
    }

    // store
    #pragma unroll
    for (int mi = 0; mi < 4; ++mi) {
        #pragma unroll
        for (int j = 0; j < 4; ++j) {
            size_t rg = (size_t)(m0 + wr * 64 + mi * 16 + l4 * 4 + j);
            #pragma unroll
            for (int ni = 0; ni < 4; ++ni) {
                int ng = n0 + wc * 64 + ni * 16 + lr;
                float v = accF[mi][ni][j];
                if (MODE == 0) {
                    v = v > 0.f ? v : expf(v) - 1.f;
                    ((short*)Out)[rg * NPAD + ng] = f2bf(v);
                } else {
                    if (ng < NREAL)
                        ((float*)Out)[rg * NREAL + ng] = v * Ynorm[NREAL + ng] + Ynorm[ng];
                }
            }
        }
    }
}

// ---------------------------------------------------------------------------
extern "C" void kernel_launch(void* const* d_in, const int* in_sizes, int n_in,
                              void* d_out, int out_size, void* d_ws, size_t ws_size,
                              hipStream_t stream) {
    const float* x     = (const float*)d_in[0];
    const float* Xnorm = (const float*)d_in[1];
    const float* Ynorm = (const float*)d_in[2];
    const float* G1W   = (const float*)d_in[3];
    const float* G1b   = (const float*)d_in[4];
    const float* G2W   = (const float*)d_in[5];
    const float* G2b   = (const float*)d_in[6];
    const float* G3W   = (const float*)d_in[7];
    const float* G3b   = (const float*)d_in[8];
    const float* W1    = (const float*)d_in[9];
    const float* b1    = (const float*)d_in[10];
    const float* W2    = (const float*)d_in[11];
    const float* b2    = (const float*)d_in[12];
    const float* W3    = (const float*)d_in[13];
    const float* b3    = (const float*)d_in[14];
    const int*   gidx  = (const int*)d_in[15];

    // workspace layout (m2 aliases xnbf: xnbf is fully consumed by layer 1)
    char* ws = (char*)d_ws;
    size_t off = 0;
    short* xnbf = (short*)(ws + off); off += (size_t)BATCH * KP * 2;        // 16.8 MB
    short* m1   = (short*)(ws + off); off += (size_t)BATCH * DH * 2;        // 16.8 MB
    short* Wt1  = (short*)(ws + off); off += (size_t)NEXP * DH  * KP * 2;   // 4.2 MB
    short* Wt2  = (short*)(ws + off); off += (size_t)NEXP * DH  * KP * 2;   // 4.2 MB
    short* Wt3  = (short*)(ws + off); off += (size_t)NEXP * 384 * KP * 2;   // 3.1 MB
    float* wg   = (float*)(ws + off); off += (size_t)BATCH * NEXP * 4;      // 0.5 MB
    short* m2   = xnbf;
    if (off > ws_size) return;

    // 1. normalize x -> bf16 (pitch 512, zero-padded)
    prep_xn_kernel<<<BATCH * 64 / 256, 256, 0, stream>>>(x, Xnorm, xnbf);

    // 2. transpose weights to [E][NPAD][KP] bf16 (K zero-padded)
    transpose_w_kernel<<<NEXP * (KP / 32) * (DH / 32), 256, 0, stream>>>(W1, Wt1, DIN, DH, DH);
    transpose_w_kernel<<<NEXP * (KP / 32) * (DH / 32), 256, 0, stream>>>(W2, Wt2, DH, DH, DH);
    transpose_w_kernel<<<NEXP * (KP / 32) * (384 / 32), 256, 0, stream>>>(W3, Wt3, DH, DOUT, 384);

    // 3. gating -> w[B][8]
    gating_kernel<<<256, 256, 0, stream>>>(x, Xnorm, G1W, G1b, G2W, G2b, G3W, G3b, gidx, wg);

    // 4. expert layers (BM=256, BN=128)
    expert_v11_kernel<DH, DH, 0>
        <<<(BATCH / 256) * (DH / 128), 512, 0, stream>>>(xnbf, Wt1, wg, b1, Ynorm, m1);
    expert_v11_kernel<DH, DH, 0>
        <<<(BATCH / 256) * (DH / 128), 512, 0, stream>>>(m1, Wt2, wg, b2, Ynorm, m2);
    expert_v11_kernel<384, DOUT, 1>
        <<<(BATCH / 256) * (384 / 128), 512, 0, stream>>>(m2, Wt3, wg, b3, Ynorm, (void*)d_out);
}

// Round 12
// 416.657 us; speedup vs baseline: 3.1511x; 3.1511x over previous
//
#include <hip/hip_runtime.h>
#include <hip/hip_bf16.h>
#include <math.h>

// Problem constants
#define BATCH 16384
#define DIN   480
#define DH    512
#define DOUT  360
#define NEXP  8
#define GIN   64
#define GH    128
#define KP    512          // padded K for all expert layers

typedef short bf16x8 __attribute__((ext_vector_type(8)));
typedef float f32x4  __attribute__((ext_vector_type(4)));

__device__ __forceinline__ short f2bf(float f) {
    __hip_bfloat16 h = __float2bfloat16(f);
    return *reinterpret_cast<short*>(&h);
}
__device__ __forceinline__ float eluf(float x) { return x > 0.f ? x : expf(x) - 1.f; }

__device__ __forceinline__ void gll16(const void* g, void* l) {
    __builtin_amdgcn_global_load_lds(
        (const __attribute__((address_space(1))) unsigned int*)g,
        (__attribute__((address_space(3))) unsigned int*)l, 16, 0, 0);
}

// packed bf16x2 multiply: a (2 bf16) * w (2 bf16, duplicated scalar)
__device__ __forceinline__ unsigned bfm2(unsigned a, unsigned w) {
    __hip_bfloat162 av = *reinterpret_cast<__hip_bfloat162*>(&a);
    __hip_bfloat162 wv = *reinterpret_cast<__hip_bfloat162*>(&w);
    __hip_bfloat162 r = __hmul2(av, wv);
    return *reinterpret_cast<unsigned*>(&r);
}
// scale a bf16x8 fragment by a duplicated-bf16 pair
__device__ __forceinline__ bf16x8 scale8(bf16x8 a, unsigned w) {
    union { bf16x8 v; unsigned u[4]; } x;
    x.v = a;
    #pragma unroll
    for (int i = 0; i < 4; ++i) x.u[i] = bfm2(x.u[i], w);
    return x.v;
}

// ---------------------------------------------------------------------------
// Kernel 1: xn = (x - mu) / sigma -> bf16, pitch 512 (cols 480..511 zero).
// ---------------------------------------------------------------------------
__global__ void prep_xn_kernel(const float* __restrict__ x,
                               const float* __restrict__ Xnorm,
                               short* __restrict__ xnbf) {
    const int tid = blockIdx.x * 256 + threadIdx.x;
    const int row = tid >> 6;
    const int c   = (tid & 63) * 8;
    short v8[8];
    if (c < DIN) {
        #pragma unroll
        for (int j = 0; j < 8; ++j) {
            float v = (x[(size_t)row * DIN + c + j] - Xnorm[c + j]) / Xnorm[DIN + c + j];
            v8[j] = f2bf(v);
        }
    } else {
        #pragma unroll
        for (int j = 0; j < 8; ++j) v8[j] = 0;
    }
    *(uint4*)&xnbf[(size_t)row * KP + c] = *(uint4*)v8;
}

// ---------------------------------------------------------------------------
// Kernel 2: transpose + convert W (E,K,N) f32 -> Wt (E,NPAD,KP) bf16, zero pad.
// ---------------------------------------------------------------------------
__global__ void transpose_w_kernel(const float* __restrict__ src,
                                   short* __restrict__ dst,
                                   int K, int N, int NPAD) {
    __shared__ float tile[32][33];
    const int ntn = NPAD / 32;
    const int ntk = KP / 32;
    int lin = blockIdx.x;
    const int e  = lin / (ntk * ntn);
    lin -= e * ntk * ntn;
    const int kt = lin / ntn;
    const int nt = lin % ntn;
    const int t = threadIdx.x;
    #pragma unroll
    for (int r = 0; r < 4; ++r) {
        int idx = t + r * 256;
        int i = idx >> 5;          // k within tile
        int j = idx & 31;          // n within tile
        int k = kt * 32 + i;
        int n = nt * 32 + j;
        float v = (n < N && k < K) ? src[((size_t)e * K + k) * N + n] : 0.f;
        tile[i][j] = v;
    }
    __syncthreads();
    #pragma unroll
    for (int r = 0; r < 4; ++r) {
        int idx = t + r * 256;
        int i2 = idx & 31;         // k (contiguous on write)
        int j2 = idx >> 5;         // n
        dst[((size_t)e * NPAD + nt * 32 + j2) * KP + kt * 32 + i2] = f2bf(tile[i2][j2]);
    }
}

// ---------------------------------------------------------------------------
// Kernel 3: gating MLP -> softmax weights w[B][8] (fp32).
// ---------------------------------------------------------------------------
__global__ __launch_bounds__(256) void gating_kernel(
    const float* __restrict__ x, const float* __restrict__ Xnorm,
    const float* __restrict__ G1W, const float* __restrict__ G1b,
    const float* __restrict__ G2W, const float* __restrict__ G2b,
    const float* __restrict__ G3W, const float* __restrict__ G3b,
    const int* __restrict__ gidx, float* __restrict__ wout) {

    __shared__ float g2s[GH * GH];
    __shared__ float g3s[GH * NEXP];
    __shared__ float b1s[GH], b2s[GH], b3s[NEXP];
    __shared__ float g0b[4][GIN], h1b[4][GH], h2b[4][GH];

    const int t = threadIdx.x;
    const int lane = t & 63;
    const int wid  = t >> 6;

    for (int i = t; i < GH * GH; i += 256) g2s[i] = G2W[i];
    for (int i = t; i < GH * NEXP; i += 256) g3s[i] = G3W[i];
    if (t < GH) { b1s[t] = G1b[t]; b2s[t] = G2b[t]; }
    if (t < NEXP) b3s[t] = G3b[t];
    __syncthreads();

    const int gi = gidx[lane];
    const float mu = Xnorm[gi];
    const float inv_sig = 1.f / Xnorm[DIN + gi];

    for (int it = 0; it < 16; ++it) {
        const int row = (blockIdx.x * 4 + wid) * 16 + it;
        float g0 = (x[(size_t)row * DIN + gi] - mu) * inv_sig;
        g0b[wid][lane] = g0;
        __syncthreads();
        float h1a = b1s[lane], h1c = b1s[lane + 64];
        #pragma unroll 8
        for (int i = 0; i < GIN; ++i) {
            float g = g0b[wid][i];
            h1a += g * G1W[i * GH + lane];
            h1c += g * G1W[i * GH + lane + 64];
        }
        h1b[wid][lane] = eluf(h1a);
        h1b[wid][lane + 64] = eluf(h1c);
        __syncthreads();
        float h2a = b2s[lane], h2c = b2s[lane + 64];
        #pragma unroll 8
        for (int i = 0; i < GH; ++i) {
            float h = h1b[wid][i];
            h2a += h * g2s[i * GH + lane];
            h2c += h * g2s[i * GH + lane + 64];
        }
        h2b[wid][lane] = eluf(h2a);
        h2b[wid][lane + 64] = eluf(h2c);
        __syncthreads();
        const int e  = lane & 7;
        const int ch = lane >> 3;
        float p = 0.f;
        #pragma unroll
        for (int i2 = 0; i2 < 16; ++i2) {
            int i = ch * 16 + i2;
            p += h2b[wid][i] * g3s[i * NEXP + e];
        }
        p += __shfl_xor(p, 8);
        p += __shfl_xor(p, 16);
        p += __shfl_xor(p, 32);
        p += b3s[e];
        float mx = p;
        mx = fmaxf(mx, __shfl_xor(mx, 1));
        mx = fmaxf(mx, __shfl_xor(mx, 2));
        mx = fmaxf(mx, __shfl_xor(mx, 4));
        float ex = expf(p - mx);
        float sm = ex;
        sm += __shfl_xor(sm, 1);
        sm += __shfl_xor(sm, 2);
        sm += __shfl_xor(sm, 4);
        float wv = ex / sm;
        if (lane < NEXP) wout[(size_t)row * NEXP + lane] = wv;
        __syncthreads();
    }
}

// ---------------------------------------------------------------------------
// Kernel 4 v12: scaled-A formulation. C = sum_{kt,e} (w_e o A)_kt @ W_e,kt:
// scale A-fragments in registers by w_e[row] (per-lane broadcast, packed
// bf16 __hmul2) and MFMA accumulates DIRECTLY into accF — no per-expert acc
// (-64 AGPR), no mix pass. Freed arch budget (cap 192) funds depth-3 B
// prefetch (4 LDS slots) + phase-0 register lookahead at STEP TOP: B(s+1)
// is complete before step s begins (drained by the vmcnt one step earlier),
// so its ds_read hides under step-s MFMAs. vmcnt (FIFO-audited, A issued
// BEFORE B at e==6): s>=61 -> 0; e==6&&kt<7 -> 6; else 2. One barrier/step.
// ---------------------------------------------------------------------------
#define ESTEP(EVAL, BCU, BCF)                                                  \
{                                                                              \
    const int e_ = (EVAL);                                                     \
    const int s_ = kt * 8 + e_;                                                \
    /* (a) issue prefetches: A first (so vmcnt(6) keeps A+B(s+3)) */           \
    if (e_ == 6 && kt < 7) {                                                   \
        const size_t oa = (size_t)(kt + 1) * 64;                               \
        _Pragma("unroll")                                                      \
        for (int i = 0; i < 4; ++i)                                            \
            gll16(baseA[i] + oa,                                               \
                  bufA0 + ((kt + 1) & 1) * (256 * 64) + (wid * 4 + i) * 512);  \
    }                                                                          \
    if (s_ < 61) {                                                             \
        const int s3 = s_ + 3;                                                 \
        const size_t ob = (size_t)(s3 & 7) * NPAD * KP + (size_t)(s3 >> 3) * 64; \
        _Pragma("unroll")                                                      \
        for (int i = 0; i < 2; ++i)                                            \
            gll16(baseB[i] + ob, bufB0 + (s3 & 3) * (128 * 64) + (wid * 2 + i) * 512); \
    }                                                                          \
    /* (b) packed gating weights for this e: one b128 read */                  \
    const uint4 wq = *(const uint4*)&wpk[wr * 512 + e_ * 64 + lr * 4];         \
    /* (g) lookahead: B(s+1) phase-0 frags (slot complete since last step) */  \
    if (s_ < 63) {                                                             \
        const short* Bn = bufB0 + ((s_ + 1) & 3) * (128 * 64);                 \
        _Pragma("unroll")                                                      \
        for (int ni = 0; ni < 4; ++ni)                                         \
            BCF[ni] = *(const bf16x8*)(Bn + brow + ni * 1024 + xo0);           \
    }                                                                          \
    /* (c) phase 0: scale af0 by w, MFMA into accF (register B, no stall) */   \
    __builtin_amdgcn_s_setprio(1);                                             \
    {                                                                          \
        unsigned wa[4] = {wq.x, wq.y, wq.z, wq.w};                             \
        _Pragma("unroll")                                                      \
        for (int mi = 0; mi < 4; ++mi) {                                       \
            bf16x8 afe = scale8(af0[mi], wa[mi]);                              \
            _Pragma("unroll")                                                  \
            for (int ni = 0; ni < 4; ++ni)                                     \
                accF[mi][ni] = __builtin_amdgcn_mfma_f32_16x16x32_bf16(        \
                    afe, BCU[ni], accF[mi][ni], 0, 0, 0);                      \
        }                                                                      \
    }                                                                          \
    __builtin_amdgcn_s_setprio(0);                                             \
    /* (d) phase 1: in-step B reads (hidden under phase-0 MFMAs) */            \
    {                                                                          \
        const short* Bb = bufB0 + (s_ & 3) * (128 * 64);                       \
        bf16x8 b1[4];                                                          \
        _Pragma("unroll")                                                      \
        for (int ni = 0; ni < 4; ++ni)                                         \
            b1[ni] = *(const bf16x8*)(Bb + brow + ni * 1024 + xo1);            \
        unsigned wa[4] = {wq.x, wq.y, wq.z, wq.w};                             \
        __builtin_amdgcn_s_setprio(1);                                         \
        _Pragma("unroll")                                                      \
        for (int mi = 0; mi < 4; ++mi) {                                       \
            bf16x8 afe = scale8(af1[mi], wa[mi]);                              \
            _Pragma("unroll")                                                  \
            for (int ni = 0; ni < 4; ++ni)                                     \
                accF[mi][ni] = __builtin_amdgcn_mfma_f32_16x16x32_bf16(        \
                    afe, b1[ni], accF[mi][ni], 0, 0, 0);                       \
        }                                                                      \
        __builtin_amdgcn_s_setprio(0);                                         \
    }                                                                          \
    /* (f) counted wait + publish barrier */                                   \
    if (s_ >= 61)               asm volatile("s_waitcnt vmcnt(0)" ::: "memory"); \
    else if (e_ == 6 && kt < 7) asm volatile("s_waitcnt vmcnt(6)" ::: "memory"); \
    else                        asm volatile("s_waitcnt vmcnt(2)" ::: "memory"); \
    asm volatile("s_barrier" ::: "memory");                                    \
}

template<int NPAD, int NREAL, int MODE>
__global__ __launch_bounds__(512, 2) void expert_v12_kernel(
    const short* __restrict__ A, const short* __restrict__ Wt,
    const float* __restrict__ wgate, const float* __restrict__ bias,
    const float* __restrict__ Ynorm, void* __restrict__ Out) {

    __shared__ __align__(16) short bufA[2][256 * 64];   // 64 KB
    __shared__ __align__(16) short bufB[4][128 * 64];   // 64 KB
    __shared__ float wlsT[NEXP][256];                   // 8 KB (epilogue)
    __shared__ unsigned wpk[4 * NEXP * 16 * 4];         // 8 KB (packed bf16 w)

    const int t = threadIdx.x;
    const int lane = t & 63;
    const int wid  = t >> 6;          // 0..7
    const int wr = wid >> 1;          // 0..3 : 64-row strip
    const int wc = wid & 1;           // 0..1 : 64-col strip
    const int l4 = lane >> 4, lr = lane & 15;

    // XCD-chunked block swizzle (grid % 8 == 0 for all layers)
    constexpr int NN = NPAD / 128;
    constexpr int nwg = (BATCH / 256) * NN;
    constexpr int cpx = nwg / 8;
    const int lb  = (blockIdx.x & 7) * cpx + (blockIdx.x >> 3);
    const int m0  = (lb / NN) * 256;
    const int n0  = (lb % NN) * 128;

    // gating weights: wlsT (f32, epilogue) + wpk (packed bf16x2, main loop)
    for (int i = t; i < NEXP * 256; i += 512) {
        int e = i >> 8, r = i & 255;
        wlsT[e][r] = wgate[(size_t)(m0 + r) * NEXP + e];
    }
    for (int i = t; i < 4 * NEXP * 16 * 4; i += 512) {
        int wr_  = i >> 9;
        int rem  = i & 511;
        int e_   = rem >> 6;
        int lr_  = (rem >> 2) & 15;
        int mi_  = rem & 3;
        float w = wgate[(size_t)(m0 + wr_ * 64 + mi_ * 16 + lr_) * NEXP + e_];
        unsigned short b = (unsigned short)f2bf(w);
        wpk[i] = ((unsigned)b << 16) | b;
    }

    // staging geometry: 16B chunk per lane; 8-row x 8-slot groups, XOR swizzle
    const int srow  = lane >> 3;              // 0..7
    const int sslot = (lane & 7) ^ srow;      // pre-swizzled source 16B-slot

    const short* baseA[4];
    #pragma unroll
    for (int i = 0; i < 4; ++i)
        baseA[i] = A + (size_t)(m0 + (wid * 4 + i) * 8 + srow) * KP + sslot * 8;
    const short* baseB[2];
    #pragma unroll
    for (int i = 0; i < 2; ++i)
        baseB[i] = Wt + (size_t)(n0 + (wid * 2 + i) * 8 + srow) * KP + sslot * 8;

    short* const bufA0 = &bufA[0][0];
    short* const bufB0 = &bufB[0][0];

    f32x4 accF[4][4];
    #pragma unroll
    for (int mi = 0; mi < 4; ++mi)
        #pragma unroll
        for (int ni = 0; ni < 4; ++ni)
            accF[mi][ni] = (f32x4){0.f, 0.f, 0.f, 0.f};

    // prologue: A(kt=0); B(0),B(1),B(2) -> slots 0,1,2; full drain once.
    #pragma unroll
    for (int i = 0; i < 4; ++i)
        gll16(baseA[i], bufA0 + (wid * 4 + i) * 512);
    #pragma unroll
    for (int s = 0; s < 3; ++s) {
        const size_t ob = (size_t)s * NPAD * KP;   // e=s, kt=0
        #pragma unroll
        for (int i = 0; i < 2; ++i)
            gll16(baseB[i] + ob, bufB0 + s * (128 * 64) + (wid * 2 + i) * 512);
    }
    __syncthreads();

    const int xo0 = (l4 * 8) ^ ((lr & 7) << 3);
    const int xo1 = (32 + l4 * 8) ^ ((lr & 7) << 3);
    const int arow = (wr * 64 + lr) * 64;      // af row base (mi adds 16*64)
    const int brow = (wc * 64 + lr) * 64;      // b  row base (ni adds 16*64)

    // initial phase-0 register fragments: B(0) from slot 0
    bf16x8 bcA[4], bcB[4];
    #pragma unroll
    for (int ni = 0; ni < 4; ++ni)
        bcA[ni] = *(const bf16x8*)(bufB0 + brow + ni * 1024 + xo0);

    #pragma unroll 1
    for (int kt = 0; kt < 8; ++kt) {
        const short* Ab = bufA0 + (kt & 1) * (256 * 64);

        // hoisted A fragments: valid for all 8 e-steps of this kt
        bf16x8 af0[4], af1[4];
        #pragma unroll
        for (int mi = 0; mi < 4; ++mi) {
            af0[mi] = *(const bf16x8*)(Ab + arow + mi * 1024 + xo0);
            af1[mi] = *(const bf16x8*)(Ab + arow + mi * 1024 + xo1);
        }

        #pragma unroll 1
        for (int ee = 0; ee < 4; ++ee) {
            ESTEP(2 * ee,     bcA, bcB)
            ESTEP(2 * ee + 1, bcB, bcA)
        }
    }

    // epilogue: rank-1 bias term  accF += sum_e w_e[row] * bias_e[col]
    {
        float bv[4][NEXP];
        #pragma unroll
        for (int ni = 0; ni < 4; ++ni) {
            int ng = n0 + wc * 64 + ni * 16 + lr;
            #pragma unroll
            for (int e = 0; e < NEXP; ++e)
                bv[ni][e] = (ng < NREAL) ? bias[(size_t)e * NREAL + ng] : 0.f;
        }
        #pragma unroll
        for (int mi = 0; mi < 4; ++mi) {
            f32x4 wve[NEXP];
            #pragma unroll
            for (int e = 0; e < NEXP; ++e)
                wve[e] = *(const f32x4*)&wlsT[e][wr * 64 + mi * 16 + l4 * 4];
            #pragma unroll
            for (int ni = 0; ni < 4; ++ni)
                #pragma unroll
                for (int j = 0; j < 4; ++j) {
                    float sum = 0.f;
                    #pragma unroll
                    for (int e = 0; e < NEXP; ++e) sum += wve[e][j] * bv[ni][e];
                    accF[mi][ni][j] += sum;
                }
        }
    }

    // store
    #pragma unroll
    for (int mi = 0; mi < 4; ++mi) {
        #pragma unroll
        for (int j = 0; j < 4; ++j) {
            size_t rg = (size_t)(m0 + wr * 64 + mi * 16 + l4 * 4 + j);
            #pragma unroll
            for (int ni = 0; ni < 4; ++ni) {
                int ng = n0 + wc * 64 + ni * 16 + lr;
                float v = accF[mi][ni][j];
                if (MODE == 0) {
                    v = v > 0.f ? v : expf(v) - 1.f;
                    ((short*)Out)[rg * NPAD + ng] = f2bf(v);
                } else {
                    if (ng < NREAL)
                        ((float*)Out)[rg * NREAL + ng] = v * Ynorm[NREAL + ng] + Ynorm[ng];
                }
            }
        }
    }
}

// ---------------------------------------------------------------------------
extern "C" void kernel_launch(void* const* d_in, const int* in_sizes, int n_in,
                              void* d_out, int out_size, void* d_ws, size_t ws_size,
                              hipStream_t stream) {
    const float* x     = (const float*)d_in[0];
    const float* Xnorm = (const float*)d_in[1];
    const float* Ynorm = (const float*)d_in[2];
    const float* G1W   = (const float*)d_in[3];
    const float* G1b   = (const float*)d_in[4];
    const float* G2W   = (const float*)d_in[5];
    const float* G2b   = (const float*)d_in[6];
    const float* G3W   = (const float*)d_in[7];
    const float* G3b   = (const float*)d_in[8];
    const float* W1    = (const float*)d_in[9];
    const float* b1    = (const float*)d_in[10];
    const float* W2    = (const float*)d_in[11];
    const float* b2    = (const float*)d_in[12];
    const float* W3    = (const float*)d_in[13];
    const float* b3    = (const float*)d_in[14];
    const int*   gidx  = (const int*)d_in[15];

    // workspace layout (m2 aliases xnbf: xnbf is fully consumed by layer 1)
    char* ws = (char*)d_ws;
    size_t off = 0;
    short* xnbf = (short*)(ws + off); off += (size_t)BATCH * KP * 2;        // 16.8 MB
    short* m1   = (short*)(ws + off); off += (size_t)BATCH * DH * 2;        // 16.8 MB
    short* Wt1  = (short*)(ws + off); off += (size_t)NEXP * DH  * KP * 2;   // 4.2 MB
    short* Wt2  = (short*)(ws + off); off += (size_t)NEXP * DH  * KP * 2;   // 4.2 MB
    short* Wt3  = (short*)(ws + off); off += (size_t)NEXP * 384 * KP * 2;   // 3.1 MB
    float* wg   = (float*)(ws + off); off += (size_t)BATCH * NEXP * 4;      // 0.5 MB
    short* m2   = xnbf;
    if (off > ws_size) return;

    // 1. normalize x -> bf16 (pitch 512, zero-padded)
    prep_xn_kernel<<<BATCH * 64 / 256, 256, 0, stream>>>(x, Xnorm, xnbf);

    // 2. transpose weights to [E][NPAD][KP] bf16 (K zero-padded)
    transpose_w_kernel<<<NEXP * (KP / 32) * (DH / 32), 256, 0, stream>>>(W1, Wt1, DIN, DH, DH);
    transpose_w_kernel<<<NEXP * (KP / 32) * (DH / 32), 256, 0, stream>>>(W2, Wt2, DH, DH, DH);
    transpose_w_kernel<<<NEXP * (KP / 32) * (384 / 32), 256, 0, stream>>>(W3, Wt3, DH, DOUT, 384);

    // 3. gating -> w[B][8]
    gating_kernel<<<256, 256, 0, stream>>>(x, Xnorm, G1W, G1b, G2W, G2b, G3W, G3b, gidx, wg);

    // 4. expert layers (BM=256, BN=128)
    expert_v12_kernel<DH, DH, 0>
        <<<(BATCH / 256) * (DH / 128), 512, 0, stream>>>(xnbf, Wt1, wg, b1, Ynorm, m1);
    expert_v12_kernel<DH, DH, 0>
        <<<(BATCH / 256) * (DH / 128), 512, 0, stream>>>(m1, Wt2, wg, b2, Ynorm, m2);
    expert_v12_kernel<384, DOUT, 1>
        <<<(BATCH / 256) * (384 / 128), 512, 0, stream>>>(m2, Wt3, wg, b3, Ynorm, (void*)d_out);
}

// Round 13
// 404.679 us; speedup vs baseline: 3.2444x; 1.0296x over previous
//
#include <hip/hip_runtime.h>
#include <hip/hip_bf16.h>
#include <math.h>

// Problem constants
#define BATCH 16384
#define DIN   480
#define DH    512
#define DOUT  360
#define NEXP  8
#define GIN   64
#define GH    128
#define KP    512          // padded K for all expert layers

typedef short bf16x8 __attribute__((ext_vector_type(8)));
typedef float f32x4  __attribute__((ext_vector_type(4)));

__device__ __forceinline__ short f2bf(float f) {
    __hip_bfloat16 h = __float2bfloat16(f);
    return *reinterpret_cast<short*>(&h);
}
__device__ __forceinline__ float eluf(float x) { return x > 0.f ? x : expf(x) - 1.f; }

__device__ __forceinline__ void gll16(const void* g, void* l) {
    __builtin_amdgcn_global_load_lds(
        (const __attribute__((address_space(1))) unsigned int*)g,
        (__attribute__((address_space(3))) unsigned int*)l, 16, 0, 0);
}

// ---------------------------------------------------------------------------
// Kernel 1: xn = (x - mu) / sigma -> bf16, pitch 512 (cols 480..511 zero).
// ---------------------------------------------------------------------------
__global__ void prep_xn_kernel(const float* __restrict__ x,
                               const float* __restrict__ Xnorm,
                               short* __restrict__ xnbf) {
    const int tid = blockIdx.x * 256 + threadIdx.x;
    const int row = tid >> 6;
    const int c   = (tid & 63) * 8;
    short v8[8];
    if (c < DIN) {
        #pragma unroll
        for (int j = 0; j < 8; ++j) {
            float v = (x[(size_t)row * DIN + c + j] - Xnorm[c + j]) / Xnorm[DIN + c + j];
            v8[j] = f2bf(v);
        }
    } else {
        #pragma unroll
        for (int j = 0; j < 8; ++j) v8[j] = 0;
    }
    *(uint4*)&xnbf[(size_t)row * KP + c] = *(uint4*)v8;
}

// ---------------------------------------------------------------------------
// Kernel 2: transpose + convert W (E,K,N) f32 -> Wt (E,NPAD,KP) bf16, zero pad.
// ---------------------------------------------------------------------------
__global__ void transpose_w_kernel(const float* __restrict__ src,
                                   short* __restrict__ dst,
                                   int K, int N, int NPAD) {
    __shared__ float tile[32][33];
    const int ntn = NPAD / 32;
    const int ntk = KP / 32;
    int lin = blockIdx.x;
    const int e  = lin / (ntk * ntn);
    lin -= e * ntk * ntn;
    const int kt = lin / ntn;
    const int nt = lin % ntn;
    const int t = threadIdx.x;
    #pragma unroll
    for (int r = 0; r < 4; ++r) {
        int idx = t + r * 256;
        int i = idx >> 5;          // k within tile
        int j = idx & 31;          // n within tile
        int k = kt * 32 + i;
        int n = nt * 32 + j;
        float v = (n < N && k < K) ? src[((size_t)e * K + k) * N + n] : 0.f;
        tile[i][j] = v;
    }
    __syncthreads();
    #pragma unroll
    for (int r = 0; r < 4; ++r) {
        int idx = t + r * 256;
        int i2 = idx & 31;         // k (contiguous on write)
        int j2 = idx >> 5;         // n
        dst[((size_t)e * NPAD + nt * 32 + j2) * KP + kt * 32 + i2] = f2bf(tile[i2][j2]);
    }
}

// ---------------------------------------------------------------------------
// Kernel 3: gating MLP -> softmax weights w[B][8] (fp32).
// ---------------------------------------------------------------------------
__global__ __launch_bounds__(256) void gating_kernel(
    const float* __restrict__ x, const float* __restrict__ Xnorm,
    const float* __restrict__ G1W, const float* __restrict__ G1b,
    const float* __restrict__ G2W, const float* __restrict__ G2b,
    const float* __restrict__ G3W, const float* __restrict__ G3b,
    const int* __restrict__ gidx, float* __restrict__ wout) {

    __shared__ float g2s[GH * GH];
    __shared__ float g3s[GH * NEXP];
    __shared__ float b1s[GH], b2s[GH], b3s[NEXP];
    __shared__ float g0b[4][GIN], h1b[4][GH], h2b[4][GH];

    const int t = threadIdx.x;
    const int lane = t & 63;
    const int wid  = t >> 6;

    for (int i = t; i < GH * GH; i += 256) g2s[i] = G2W[i];
    for (int i = t; i < GH * NEXP; i += 256) g3s[i] = G3W[i];
    if (t < GH) { b1s[t] = G1b[t]; b2s[t] = G2b[t]; }
    if (t < NEXP) b3s[t] = G3b[t];
    __syncthreads();

    const int gi = gidx[lane];
    const float mu = Xnorm[gi];
    const float inv_sig = 1.f / Xnorm[DIN + gi];

    for (int it = 0; it < 16; ++it) {
        const int row = (blockIdx.x * 4 + wid) * 16 + it;
        float g0 = (x[(size_t)row * DIN + gi] - mu) * inv_sig;
        g0b[wid][lane] = g0;
        __syncthreads();
        float h1a = b1s[lane], h1c = b1s[lane + 64];
        #pragma unroll 8
        for (int i = 0; i < GIN; ++i) {
            float g = g0b[wid][i];
            h1a += g * G1W[i * GH + lane];
            h1c += g * G1W[i * GH + lane + 64];
        }
        h1b[wid][lane] = eluf(h1a);
        h1b[wid][lane + 64] = eluf(h1c);
        __syncthreads();
        float h2a = b2s[lane], h2c = b2s[lane + 64];
        #pragma unroll 8
        for (int i = 0; i < GH; ++i) {
            float h = h1b[wid][i];
            h2a += h * g2s[i * GH + lane];
            h2c += h * g2s[i * GH + lane + 64];
        }
        h2b[wid][lane] = eluf(h2a);
        h2b[wid][lane + 64] = eluf(h2c);
        __syncthreads();
        const int e  = lane & 7;
        const int ch = lane >> 3;
        float p = 0.f;
        #pragma unroll
        for (int i2 = 0; i2 < 16; ++i2) {
            int i = ch * 16 + i2;
            p += h2b[wid][i] * g3s[i * NEXP + e];
        }
        p += __shfl_xor(p, 8);
        p += __shfl_xor(p, 16);
        p += __shfl_xor(p, 32);
        p += b3s[e];
        float mx = p;
        mx = fmaxf(mx, __shfl_xor(mx, 1));
        mx = fmaxf(mx, __shfl_xor(mx, 2));
        mx = fmaxf(mx, __shfl_xor(mx, 4));
        float ex = expf(p - mx);
        float sm = ex;
        sm += __shfl_xor(sm, 1);
        sm += __shfl_xor(sm, 2);
        sm += __shfl_xor(sm, 4);
        float wv = ex / sm;
        if (lane < NEXP) wout[(size_t)row * NEXP + lane] = wv;
        __syncthreads();
    }
}

// ---------------------------------------------------------------------------
// Kernel 4 v13: per-kt full-expert staging + BARRIER-FREE skewed e-loop.
// BM=128, BN=128, 8 waves (2M x 4N -> wave tile 64x32), 512 threads.
// Per kt: barrier; stage A(kt) + ALL 8 B(e,kt) tiles (18 gll/thread);
// vmcnt(0); barrier; then 8 e-steps with NO synchronization, each wave in
// rotated expert order e=(wid+j)&7 -> waves on one SIMD are 4 experts apart,
// ds-bursts and MFMA-bursts anti-align across waves. 16 barriers total.
// acc[4][2]+accF[4][2]=64 AGPR; A-frags hoisted per kt; gating weights as
// packed-bf16 pairs in a broadcast LDS table (2 reads/step; bf16 w numerics
// validated by v12's identical absmax). LDS = 16+128+4+2 = 150 KB.
// ---------------------------------------------------------------------------
template<int NPAD, int NREAL, int MODE>
__global__ __launch_bounds__(512, 1) void expert_v13_kernel(
    const short* __restrict__ A, const short* __restrict__ Wt,
    const float* __restrict__ wgate, const float* __restrict__ bias,
    const float* __restrict__ Ynorm, void* __restrict__ Out) {

    __shared__ __align__(16) short bufA[128 * 64];        // 16 KB
    __shared__ __align__(16) short bufB[NEXP][128 * 64];  // 128 KB
    __shared__ float    wlsT[NEXP][128];                  // 4 KB (epilogue)
    __shared__ unsigned wpk2[512];                        // 2 KB (packed bf16 w)

    const int t = threadIdx.x;
    const int lane = t & 63;
    const int wid  = t >> 6;          // 0..7
    const int wr = wid >> 2;          // 0..1 : 64-row strip
    const int wc = wid & 3;           // 0..3 : 32-col strip
    const int l4 = lane >> 4, lr = lane & 15;

    // XCD-chunked block swizzle (grid % 8 == 0 for all layers)
    constexpr int NN = NPAD / 128;
    constexpr int nwg = (BATCH / 128) * NN;
    constexpr int cpx = nwg / 8;
    const int lb  = (blockIdx.x & 7) * cpx + (blockIdx.x >> 3);
    const int m0  = (lb / NN) * 128;
    const int n0  = (lb % NN) * 128;

    // gating weights: wlsT (f32, epilogue) + wpk2 (packed bf16 pairs, mix).
    // wpk2 layout: [((e*2+wr)*4+l4)*8 + mi*2 + p] = pack(w[row], w[row+1]),
    // row = wr*64 + mi*16 + l4*4 + p*2. All 16 lr-lanes read same addr.
    for (int i = t; i < NEXP * 128; i += 512) {
        int e = i >> 7, r = i & 127;
        wlsT[e][r] = wgate[(size_t)(m0 + r) * NEXP + e];
    }
    {
        int e = t >> 6, wr_ = (t >> 5) & 1, l4_ = (t >> 3) & 3, q = t & 7;
        int mi_ = q >> 1, p = q & 1;
        int r = wr_ * 64 + mi_ * 16 + l4_ * 4 + p * 2;
        unsigned short b0 = (unsigned short)f2bf(wgate[(size_t)(m0 + r) * NEXP + e]);
        unsigned short b1 = (unsigned short)f2bf(wgate[(size_t)(m0 + r + 1) * NEXP + e]);
        wpk2[t] = ((unsigned)b1 << 16) | b0;
    }

    // staging geometry: per thread 2 chunks per tile; c = wid*128 + j2*64 + lane
    const int c0 = wid * 128 + lane;
    const int c1 = c0 + 64;
    const int r0 = c0 >> 3, s0 = (c0 & 7) ^ (r0 & 7);
    const int r1 = c1 >> 3, s1 = (c1 & 7) ^ (r1 & 7);

    const short* srcA0 = A + (size_t)(m0 + r0) * KP + s0 * 8;
    const short* srcA1 = A + (size_t)(m0 + r1) * KP + s1 * 8;
    const short* srcB0 = Wt + (size_t)(n0 + r0) * KP + s0 * 8;
    const short* srcB1 = Wt + (size_t)(n0 + r1) * KP + s1 * 8;
    short* const dstA0 = &bufA[c0 * 8];
    short* const dstA1 = &bufA[c1 * 8];

    f32x4 acc[4][2], accF[4][2];
    #pragma unroll
    for (int mi = 0; mi < 4; ++mi)
        #pragma unroll
        for (int ni = 0; ni < 2; ++ni)
            accF[mi][ni] = (f32x4){0.f, 0.f, 0.f, 0.f};
    const f32x4 zf = (f32x4){0.f, 0.f, 0.f, 0.f};

    const int xo0 = (l4 * 8) ^ ((lr & 7) << 3);
    const int xo1 = (32 + l4 * 8) ^ ((lr & 7) << 3);
    const int arow = (wr * 64 + lr) * 64;      // + mi*16*64
    const int brow = (wc * 32 + lr) * 64;      // + ni*16*64
    const int wbase = ((0 * 2 + wr) * 4 + l4) * 8;   // + e*64 later

    #pragma unroll 1
    for (int kt = 0; kt < 8; ++kt) {
        // barrier 1: all waves done reading previous kt's LDS (reads are
        // consumed -> lgkm-waited before each wave arrives here).
        __syncthreads();

        // stage A(kt) + all 8 B(e,kt): 18 gll per thread
        const size_t ko = (size_t)kt * 64;
        gll16(srcA0 + ko, dstA0);
        gll16(srcA1 + ko, dstA1);
        #pragma unroll
        for (int e = 0; e < NEXP; ++e) {
            const size_t eo = (size_t)e * NPAD * KP + ko;
            gll16(srcB0 + eo, &bufB[e][c0 * 8]);
            gll16(srcB1 + eo, &bufB[e][c1 * 8]);
        }
        asm volatile("s_waitcnt vmcnt(0)" ::: "memory");
        asm volatile("s_barrier" ::: "memory");

        // hoisted A fragments (valid for all 8 e-steps of this kt)
        bf16x8 af0[4], af1[4];
        #pragma unroll
        for (int mi = 0; mi < 4; ++mi) {
            af0[mi] = *(const bf16x8*)(&bufA[arow + mi * 1024 + xo0]);
            af1[mi] = *(const bf16x8*)(&bufA[arow + mi * 1024 + xo1]);
        }

        // 8 e-steps, wave-rotated order, NO barriers
        #pragma unroll 1
        for (int j = 0; j < 8; ++j) {
            const int e_ = (wid + j) & 7;
            const short* Bb = &bufB[e_][0];

            // B fragments (4 x b128)
            bf16x8 b00, b01, b10, b11;
            b00 = *(const bf16x8*)(Bb + brow + 0 * 1024 + xo0);
            b01 = *(const bf16x8*)(Bb + brow + 1 * 1024 + xo0);
            b10 = *(const bf16x8*)(Bb + brow + 0 * 1024 + xo1);
            b11 = *(const bf16x8*)(Bb + brow + 1 * 1024 + xo1);

            __builtin_amdgcn_s_setprio(1);
            #pragma unroll
            for (int mi = 0; mi < 4; ++mi) {
                acc[mi][0] = __builtin_amdgcn_mfma_f32_16x16x32_bf16(af0[mi], b00, zf, 0, 0, 0);
                acc[mi][1] = __builtin_amdgcn_mfma_f32_16x16x32_bf16(af0[mi], b01, zf, 0, 0, 0);
            }
            #pragma unroll
            for (int mi = 0; mi < 4; ++mi) {
                acc[mi][0] = __builtin_amdgcn_mfma_f32_16x16x32_bf16(af1[mi], b10, acc[mi][0], 0, 0, 0);
                acc[mi][1] = __builtin_amdgcn_mfma_f32_16x16x32_bf16(af1[mi], b11, acc[mi][1], 0, 0, 0);
            }
            __builtin_amdgcn_s_setprio(0);

            // mix: accF += w_e[row] * acc  (w from broadcast LDS, packed bf16)
            {
                const int wb = wbase + e_ * 64;
                uint4 uq0 = *(const uint4*)&wpk2[wb];
                uint4 uq1 = *(const uint4*)&wpk2[wb + 4];
                unsigned uu[8] = {uq0.x, uq0.y, uq0.z, uq0.w,
                                  uq1.x, uq1.y, uq1.z, uq1.w};
                #pragma unroll
                for (int mi = 0; mi < 4; ++mi)
                    #pragma unroll
                    for (int p = 0; p < 2; ++p) {
                        const unsigned u = uu[mi * 2 + p];
                        const float w0 = __uint_as_float(u << 16);
                        const float w1 = __uint_as_float(u & 0xffff0000u);
                        accF[mi][0][p * 2]     += w0 * acc[mi][0][p * 2];
                        accF[mi][1][p * 2]     += w0 * acc[mi][1][p * 2];
                        accF[mi][0][p * 2 + 1] += w1 * acc[mi][0][p * 2 + 1];
                        accF[mi][1][p * 2 + 1] += w1 * acc[mi][1][p * 2 + 1];
                    }
            }
        }
    }

    // epilogue: rank-1 bias term  accF += sum_e w_e[row] * bias_e[col]
    {
        float bv[2][NEXP];
        #pragma unroll
        for (int ni = 0; ni < 2; ++ni) {
            int ng = n0 + wc * 32 + ni * 16 + lr;
            #pragma unroll
            for (int e = 0; e < NEXP; ++e)
                bv[ni][e] = (ng < NREAL) ? bias[(size_t)e * NREAL + ng] : 0.f;
        }
        #pragma unroll
        for (int mi = 0; mi < 4; ++mi) {
            f32x4 wve[NEXP];
            #pragma unroll
            for (int e = 0; e < NEXP; ++e)
                wve[e] = *(const f32x4*)&wlsT[e][wr * 64 + mi * 16 + l4 * 4];
            #pragma unroll
            for (int ni = 0; ni < 2; ++ni)
                #pragma unroll
                for (int j = 0; j < 4; ++j) {
                    float sum = 0.f;
                    #pragma unroll
                    for (int e = 0; e < NEXP; ++e) sum += wve[e][j] * bv[ni][e];
                    accF[mi][ni][j] += sum;
                }
        }
    }

    // store
    #pragma unroll
    for (int mi = 0; mi < 4; ++mi) {
        #pragma unroll
        for (int j = 0; j < 4; ++j) {
            size_t rg = (size_t)(m0 + wr * 64 + mi * 16 + l4 * 4 + j);
            #pragma unroll
            for (int ni = 0; ni < 2; ++ni) {
                int ng = n0 + wc * 32 + ni * 16 + lr;
                float v = accF[mi][ni][j];
                if (MODE == 0) {
                    v = v > 0.f ? v : expf(v) - 1.f;
                    ((short*)Out)[rg * NPAD + ng] = f2bf(v);
                } else {
                    if (ng < NREAL)
                        ((float*)Out)[rg * NREAL + ng] = v * Ynorm[NREAL + ng] + Ynorm[ng];
                }
            }
        }
    }
}

// ---------------------------------------------------------------------------
extern "C" void kernel_launch(void* const* d_in, const int* in_sizes, int n_in,
                              void* d_out, int out_size, void* d_ws, size_t ws_size,
                              hipStream_t stream) {
    const float* x     = (const float*)d_in[0];
    const float* Xnorm = (const float*)d_in[1];
    const float* Ynorm = (const float*)d_in[2];
    const float* G1W   = (const float*)d_in[3];
    const float* G1b   = (const float*)d_in[4];
    const float* G2W   = (const float*)d_in[5];
    const float* G2b   = (const float*)d_in[6];
    const float* G3W   = (const float*)d_in[7];
    const float* G3b   = (const float*)d_in[8];
    const float* W1    = (const float*)d_in[9];
    const float* b1    = (const float*)d_in[10];
    const float* W2    = (const float*)d_in[11];
    const float* b2    = (const float*)d_in[12];
    const float* W3    = (const float*)d_in[13];
    const float* b3    = (const float*)d_in[14];
    const int*   gidx  = (const int*)d_in[15];

    // workspace layout (m2 aliases xnbf: xnbf is fully consumed by layer 1)
    char* ws = (char*)d_ws;
    size_t off = 0;
    short* xnbf = (short*)(ws + off); off += (size_t)BATCH * KP * 2;        // 16.8 MB
    short* m1   = (short*)(ws + off); off += (size_t)BATCH * DH * 2;        // 16.8 MB
    short* Wt1  = (short*)(ws + off); off += (size_t)NEXP * DH  * KP * 2;   // 4.2 MB
    short* Wt2  = (short*)(ws + off); off += (size_t)NEXP * DH  * KP * 2;   // 4.2 MB
    short* Wt3  = (short*)(ws + off); off += (size_t)NEXP * 384 * KP * 2;   // 3.1 MB
    float* wg   = (float*)(ws + off); off += (size_t)BATCH * NEXP * 4;      // 0.5 MB
    short* m2   = xnbf;
    if (off > ws_size) return;

    // 1. normalize x -> bf16 (pitch 512, zero-padded)
    prep_xn_kernel<<<BATCH * 64 / 256, 256, 0, stream>>>(x, Xnorm, xnbf);

    // 2. transpose weights to [E][NPAD][KP] bf16 (K zero-padded)
    transpose_w_kernel<<<NEXP * (KP / 32) * (DH / 32), 256, 0, stream>>>(W1, Wt1, DIN, DH, DH);
    transpose_w_kernel<<<NEXP * (KP / 32) * (DH / 32), 256, 0, stream>>>(W2, Wt2, DH, DH, DH);
    transpose_w_kernel<<<NEXP * (KP / 32) * (384 / 32), 256, 0, stream>>>(W3, Wt3, DH, DOUT, 384);

    // 3. gating -> w[B][8]
    gating_kernel<<<256, 256, 0, stream>>>(x, Xnorm, G1W, G1b, G2W, G2b, G3W, G3b, gidx, wg);

    // 4. expert layers (BM=128, BN=128)
    expert_v13_kernel<DH, DH, 0>
        <<<(BATCH / 128) * (DH / 128), 512, 0, stream>>>(xnbf, Wt1, wg, b1, Ynorm, m1);
    expert_v13_kernel<DH, DH, 0>
        <<<(BATCH / 128) * (DH / 128), 512, 0, stream>>>(m1, Wt2, wg, b2, Ynorm, m2);
    expert_v13_kernel<384, DOUT, 1>
        <<<(BATCH / 128) * (384 / 128), 512, 0, stream>>>(m2, Wt3, wg, b3, Ynorm, (void*)d_out);
}

// Round 14
// 343.337 us; speedup vs baseline: 3.8240x; 1.1787x over previous
//
#include <hip/hip_runtime.h>
#include <hip/hip_bf16.h>
#include <math.h>

// Problem constants
#define BATCH 16384
#define DIN   480
#define DH    512
#define DOUT  360
#define NEXP  8
#define GIN   64
#define GH    128
#define KP    512          // padded K for all expert layers

typedef short bf16x8 __attribute__((ext_vector_type(8)));
typedef float f32x4  __attribute__((ext_vector_type(4)));

__device__ __forceinline__ short f2bf(float f) {
    __hip_bfloat16 h = __float2bfloat16(f);
    return *reinterpret_cast<short*>(&h);
}
__device__ __forceinline__ float eluf(float x) { return x > 0.f ? x : expf(x) - 1.f; }

__device__ __forceinline__ void gll16(const void* g, void* l) {
    __builtin_amdgcn_global_load_lds(
        (const __attribute__((address_space(1))) unsigned int*)g,
        (__attribute__((address_space(3))) unsigned int*)l, 16, 0, 0);
}

// ---------------------------------------------------------------------------
// Kernel 1: xn = (x - mu) / sigma -> bf16, pitch 512 (cols 480..511 zero).
// ---------------------------------------------------------------------------
__global__ void prep_xn_kernel(const float* __restrict__ x,
                               const float* __restrict__ Xnorm,
                               short* __restrict__ xnbf) {
    const int tid = blockIdx.x * 256 + threadIdx.x;
    const int row = tid >> 6;
    const int c   = (tid & 63) * 8;
    short v8[8];
    if (c < DIN) {
        #pragma unroll
        for (int j = 0; j < 8; ++j) {
            float v = (x[(size_t)row * DIN + c + j] - Xnorm[c + j]) / Xnorm[DIN + c + j];
            v8[j] = f2bf(v);
        }
    } else {
        #pragma unroll
        for (int j = 0; j < 8; ++j) v8[j] = 0;
    }
    *(uint4*)&xnbf[(size_t)row * KP + c] = *(uint4*)v8;
}

// ---------------------------------------------------------------------------
// Kernel 2: transpose + convert W (E,K,N) f32 -> Wt (E,NPAD,KP) bf16, zero pad.
// ---------------------------------------------------------------------------
__global__ void transpose_w_kernel(const float* __restrict__ src,
                                   short* __restrict__ dst,
                                   int K, int N, int NPAD) {
    __shared__ float tile[32][33];
    const int ntn = NPAD / 32;
    const int ntk = KP / 32;
    int lin = blockIdx.x;
    const int e  = lin / (ntk * ntn);
    lin -= e * ntk * ntn;
    const int kt = lin / ntn;
    const int nt = lin % ntn;
    const int t = threadIdx.x;
    #pragma unroll
    for (int r = 0; r < 4; ++r) {
        int idx = t + r * 256;
        int i = idx >> 5;          // k within tile
        int j = idx & 31;          // n within tile
        int k = kt * 32 + i;
        int n = nt * 32 + j;
        float v = (n < N && k < K) ? src[((size_t)e * K + k) * N + n] : 0.f;
        tile[i][j] = v;
    }
    __syncthreads();
    #pragma unroll
    for (int r = 0; r < 4; ++r) {
        int idx = t + r * 256;
        int i2 = idx & 31;         // k (contiguous on write)
        int j2 = idx >> 5;         // n
        dst[((size_t)e * NPAD + nt * 32 + j2) * KP + kt * 32 + i2] = f2bf(tile[i2][j2]);
    }
}

// ---------------------------------------------------------------------------
// Kernel 3: gating MLP -> softmax weights w[B][8] (fp32).
// ---------------------------------------------------------------------------
__global__ __launch_bounds__(256) void gating_kernel(
    const float* __restrict__ x, const float* __restrict__ Xnorm,
    const float* __restrict__ G1W, const float* __restrict__ G1b,
    const float* __restrict__ G2W, const float* __restrict__ G2b,
    const float* __restrict__ G3W, const float* __restrict__ G3b,
    const int* __restrict__ gidx, float* __restrict__ wout) {

    __shared__ float g2s[GH * GH];
    __shared__ float g3s[GH * NEXP];
    __shared__ float b1s[GH], b2s[GH], b3s[NEXP];
    __shared__ float g0b[4][GIN], h1b[4][GH], h2b[4][GH];

    const int t = threadIdx.x;
    const int lane = t & 63;
    const int wid  = t >> 6;

    for (int i = t; i < GH * GH; i += 256) g2s[i] = G2W[i];
    for (int i = t; i < GH * NEXP; i += 256) g3s[i] = G3W[i];
    if (t < GH) { b1s[t] = G1b[t]; b2s[t] = G2b[t]; }
    if (t < NEXP) b3s[t] = G3b[t];
    __syncthreads();

    const int gi = gidx[lane];
    const float mu = Xnorm[gi];
    const float inv_sig = 1.f / Xnorm[DIN + gi];

    for (int it = 0; it < 16; ++it) {
        const int row = (blockIdx.x * 4 + wid) * 16 + it;
        float g0 = (x[(size_t)row * DIN + gi] - mu) * inv_sig;
        g0b[wid][lane] = g0;
        __syncthreads();
        float h1a = b1s[lane], h1c = b1s[lane + 64];
        #pragma unroll 8
        for (int i = 0; i < GIN; ++i) {
            float g = g0b[wid][i];
            h1a += g * G1W[i * GH + lane];
            h1c += g * G1W[i * GH + lane + 64];
        }
        h1b[wid][lane] = eluf(h1a);
        h1b[wid][lane + 64] = eluf(h1c);
        __syncthreads();
        float h2a = b2s[lane], h2c = b2s[lane + 64];
        #pragma unroll 8
        for (int i = 0; i < GH; ++i) {
            float h = h1b[wid][i];
            h2a += h * g2s[i * GH + lane];
            h2c += h * g2s[i * GH + lane + 64];
        }
        h2b[wid][lane] = eluf(h2a);
        h2b[wid][lane + 64] = eluf(h2c);
        __syncthreads();
        const int e  = lane & 7;
        const int ch = lane >> 3;
        float p = 0.f;
        #pragma unroll
        for (int i2 = 0; i2 < 16; ++i2) {
            int i = ch * 16 + i2;
            p += h2b[wid][i] * g3s[i * NEXP + e];
        }
        p += __shfl_xor(p, 8);
        p += __shfl_xor(p, 16);
        p += __shfl_xor(p, 32);
        p += b3s[e];
        float mx = p;
        mx = fmaxf(mx, __shfl_xor(mx, 1));
        mx = fmaxf(mx, __shfl_xor(mx, 2));
        mx = fmaxf(mx, __shfl_xor(mx, 4));
        float ex = expf(p - mx);
        float sm = ex;
        sm += __shfl_xor(sm, 1);
        sm += __shfl_xor(sm, 2);
        sm += __shfl_xor(sm, 4);
        float wv = ex / sm;
        if (lane < NEXP) wout[(size_t)row * NEXP + lane] = wv;
        __syncthreads();
    }
}

// ---------------------------------------------------------------------------
// Kernel 4 v14: v8 dataflow + m201-style per-phase interleave.
// BM=256, BN=128, kt-outer / e-inner; A hoisted to regs once per kt;
// B triple-buffered, 2-deep gll prefetch; v8's FIFO-audited vmcnt rotation.
// Each (kt,e) step = 2 phases (ni-pairs). Phase = { 4x ds_read_b128 ->
// [phase0: gll issue] -> s_barrier -> lgkmcnt(0) -> setprio1 + 16 MFMA +
// setprio0 -> [phase1: end-of-step vmcnt] -> s_barrier -> 16-wide mix }.
// acc is PHASE-LOCAL [4][2] (-32 AGPR vs v8). The issue->barrier->wait
// split lets one wave's ds_reads fly under the other wave's MFMA cluster
// (the m201/m196 lever).
// ---------------------------------------------------------------------------
#define ESTEP(EVAL)                                                            \
{                                                                              \
    const int e_ = (EVAL);                                                     \
    const int s_ = kt * 8 + e_;                                                \
    const short* Bb = bufB0 + kB * (128 * 64);                                 \
    const int kB2 = (kB >= 1) ? kB - 1 : kB + 2;   /* (s+2) % 3 */             \
    f32x4 wv[4];                                                               \
    _Pragma("unroll")                                                          \
    for (int mi = 0; mi < 4; ++mi)                                             \
        wv[mi] = *(const f32x4*)&wlsT[e_][wr * 64 + mi * 16 + l4 * 4];         \
    /* ================= PHASE 0 : ni = 0,1 ================= */               \
    {                                                                          \
        bf16x8 b0a = *(const bf16x8*)(Bb + brow + 0 * 1024 + xo0);             \
        bf16x8 b0b = *(const bf16x8*)(Bb + brow + 1 * 1024 + xo0);             \
        bf16x8 b1a = *(const bf16x8*)(Bb + brow + 0 * 1024 + xo1);             \
        bf16x8 b1b = *(const bf16x8*)(Bb + brow + 1 * 1024 + xo1);             \
        if (s_ < 62) {                                                         \
            const int s2 = s_ + 2;                                             \
            const size_t ob = (size_t)(s2 & 7) * NPAD * KP + (size_t)(s2 >> 3) * 64; \
            _Pragma("unroll")                                                  \
            for (int i = 0; i < 2; ++i)                                        \
                gll16(baseB[i] + ob, bufB0 + kB2 * (128 * 64) + (wid * 2 + i) * 512); \
        }                                                                      \
        if (e_ == 6 && kt < 7) {                                               \
            const size_t oa = (size_t)(kt + 1) * 64;                           \
            _Pragma("unroll")                                                  \
            for (int i = 0; i < 4; ++i)                                        \
                gll16(baseA[i] + oa,                                           \
                      bufA0 + ((kt + 1) & 1) * (256 * 64) + (wid * 4 + i) * 512); \
        }                                                                      \
        asm volatile("s_barrier" ::: "memory");                                \
        asm volatile("s_waitcnt lgkmcnt(0)" ::: "memory");                     \
        f32x4 acc[4][2];                                                       \
        __builtin_amdgcn_s_setprio(1);                                         \
        _Pragma("unroll")                                                      \
        for (int mi = 0; mi < 4; ++mi) {                                       \
            acc[mi][0] = __builtin_amdgcn_mfma_f32_16x16x32_bf16(af0[mi], b0a, zf, 0, 0, 0); \
            acc[mi][1] = __builtin_amdgcn_mfma_f32_16x16x32_bf16(af0[mi], b0b, zf, 0, 0, 0); \
        }                                                                      \
        _Pragma("unroll")                                                      \
        for (int mi = 0; mi < 4; ++mi) {                                       \
            acc[mi][0] = __builtin_amdgcn_mfma_f32_16x16x32_bf16(af1[mi], b1a, acc[mi][0], 0, 0, 0); \
            acc[mi][1] = __builtin_amdgcn_mfma_f32_16x16x32_bf16(af1[mi], b1b, acc[mi][1], 0, 0, 0); \
        }                                                                      \
        __builtin_amdgcn_s_setprio(0);                                         \
        asm volatile("s_barrier" ::: "memory");                                \
        _Pragma("unroll")                                                      \
        for (int mi = 0; mi < 4; ++mi)                                         \
            _Pragma("unroll")                                                  \
            for (int j = 0; j < 4; ++j) {                                      \
                accF[mi][0][j] += wv[mi][j] * acc[mi][0][j];                   \
                accF[mi][1][j] += wv[mi][j] * acc[mi][1][j];                   \
            }                                                                  \
    }                                                                          \
    /* ================= PHASE 1 : ni = 2,3 ================= */               \
    {                                                                          \
        bf16x8 b0a = *(const bf16x8*)(Bb + brow + 2 * 1024 + xo0);             \
        bf16x8 b0b = *(const bf16x8*)(Bb + brow + 3 * 1024 + xo0);             \
        bf16x8 b1a = *(const bf16x8*)(Bb + brow + 2 * 1024 + xo1);             \
        bf16x8 b1b = *(const bf16x8*)(Bb + brow + 3 * 1024 + xo1);             \
        asm volatile("s_barrier" ::: "memory");                                \
        asm volatile("s_waitcnt lgkmcnt(0)" ::: "memory");                     \
        f32x4 acc[4][2];                                                       \
        __builtin_amdgcn_s_setprio(1);                                         \
        _Pragma("unroll")                                                      \
        for (int mi = 0; mi < 4; ++mi) {                                       \
            acc[mi][0] = __builtin_amdgcn_mfma_f32_16x16x32_bf16(af0[mi], b0a, zf, 0, 0, 0); \
            acc[mi][1] = __builtin_amdgcn_mfma_f32_16x16x32_bf16(af0[mi], b0b, zf, 0, 0, 0); \
        }                                                                      \
        _Pragma("unroll")                                                      \
        for (int mi = 0; mi < 4; ++mi) {                                       \
            acc[mi][0] = __builtin_amdgcn_mfma_f32_16x16x32_bf16(af1[mi], b1a, acc[mi][0], 0, 0, 0); \
            acc[mi][1] = __builtin_amdgcn_mfma_f32_16x16x32_bf16(af1[mi], b1b, acc[mi][1], 0, 0, 0); \
        }                                                                      \
        __builtin_amdgcn_s_setprio(0);                                         \
        if (kt == 7 && e_ >= 6)     asm volatile("s_waitcnt vmcnt(0)" ::: "memory"); \
        else if (e_ == 6)           asm volatile("s_waitcnt vmcnt(6)" ::: "memory"); \
        else                        asm volatile("s_waitcnt vmcnt(2)" ::: "memory"); \
        asm volatile("s_barrier" ::: "memory");                                \
        _Pragma("unroll")                                                      \
        for (int mi = 0; mi < 4; ++mi)                                         \
            _Pragma("unroll")                                                  \
            for (int j = 0; j < 4; ++j) {                                      \
                accF[mi][2][j] += wv[mi][j] * acc[mi][0][j];                   \
                accF[mi][3][j] += wv[mi][j] * acc[mi][1][j];                   \
            }                                                                  \
    }                                                                          \
    kB = (kB == 2) ? 0 : kB + 1;                                               \
}

template<int NPAD, int NREAL, int MODE>
__global__ __launch_bounds__(512, 2) void expert_v14_kernel(
    const short* __restrict__ A, const short* __restrict__ Wt,
    const float* __restrict__ wgate, const float* __restrict__ bias,
    const float* __restrict__ Ynorm, void* __restrict__ Out) {

    __shared__ __align__(16) short bufA[2][256 * 64];   // 64 KB
    __shared__ __align__(16) short bufB[3][128 * 64];   // 48 KB
    __shared__ float wlsT[NEXP][256];                   // 8 KB

    const int t = threadIdx.x;
    const int lane = t & 63;
    const int wid  = t >> 6;          // 0..7
    const int wr = wid >> 1;          // 0..3 : 64-row strip
    const int wc = wid & 1;           // 0..1 : 64-col strip
    const int l4 = lane >> 4, lr = lane & 15;

    // XCD-chunked block swizzle (grid % 8 == 0 for all layers)
    constexpr int NN = NPAD / 128;
    constexpr int nwg = (BATCH / 256) * NN;
    constexpr int cpx = nwg / 8;
    const int lb  = (blockIdx.x & 7) * cpx + (blockIdx.x >> 3);
    const int m0  = (lb / NN) * 256;
    const int n0  = (lb % NN) * 128;

    // gating weights transposed: wlsT[e][row] = wgate[(m0+row)*8+e]
    for (int i = t; i < NEXP * 256; i += 512) {
        int e = i >> 8, r = i & 255;
        wlsT[e][r] = wgate[(size_t)(m0 + r) * NEXP + e];
    }

    // staging geometry: 16B chunk per lane; 8-row x 8-slot groups, XOR swizzle
    const int srow  = lane >> 3;              // 0..7
    const int sslot = (lane & 7) ^ srow;      // pre-swizzled source 16B-slot

    const short* baseA[4];
    #pragma unroll
    for (int i = 0; i < 4; ++i)
        baseA[i] = A + (size_t)(m0 + (wid * 4 + i) * 8 + srow) * KP + sslot * 8;
    const short* baseB[2];
    #pragma unroll
    for (int i = 0; i < 2; ++i)
        baseB[i] = Wt + (size_t)(n0 + (wid * 2 + i) * 8 + srow) * KP + sslot * 8;

    short* const bufA0 = &bufA[0][0];
    short* const bufB0 = &bufB[0][0];

    f32x4 accF[4][4];
    #pragma unroll
    for (int mi = 0; mi < 4; ++mi)
        #pragma unroll
        for (int ni = 0; ni < 4; ++ni)
            accF[mi][ni] = (f32x4){0.f, 0.f, 0.f, 0.f};
    const f32x4 zf = (f32x4){0.f, 0.f, 0.f, 0.f};

    // prologue: A(kt=0) -> bufA[0]; B(s=0) -> bufB[0]; B(s=1) -> bufB[1]; drain.
    #pragma unroll
    for (int i = 0; i < 4; ++i)
        gll16(baseA[i], bufA0 + (wid * 4 + i) * 512);
    #pragma unroll
    for (int i = 0; i < 2; ++i)
        gll16(baseB[i], bufB0 + (wid * 2 + i) * 512);
    #pragma unroll
    for (int i = 0; i < 2; ++i)
        gll16(baseB[i] + (size_t)NPAD * KP, bufB0 + 128 * 64 + (wid * 2 + i) * 512);
    __syncthreads();

    const int xo0 = (l4 * 8) ^ ((lr & 7) << 3);
    const int xo1 = (32 + l4 * 8) ^ ((lr & 7) << 3);
    const int arow = (wr * 64 + lr) * 64;      // af row base (mi adds 16*64)
    const int brow = (wc * 64 + lr) * 64;      // b  row base (ni adds 16*64)

    int kB = 0;                                    // s % 3
    #pragma unroll 1
    for (int kt = 0; kt < 8; ++kt) {
        const short* Ab = bufA0 + (kt & 1) * (256 * 64);

        // hoisted A fragments: valid for all 8 e-steps of this kt
        bf16x8 af0[4], af1[4];
        #pragma unroll
        for (int mi = 0; mi < 4; ++mi) {
            af0[mi] = *(const bf16x8*)(Ab + arow + mi * 1024 + xo0);
            af1[mi] = *(const bf16x8*)(Ab + arow + mi * 1024 + xo1);
        }

        #pragma unroll 1
        for (int e = 0; e < 8; ++e) {
            ESTEP(e)
        }
    }

    // epilogue: rank-1 bias term  accF += sum_e w_e[row] * bias_e[col]
    {
        float bv[4][NEXP];
        #pragma unroll
        for (int ni = 0; ni < 4; ++ni) {
            int ng = n0 + wc * 64 + ni * 16 + lr;
            #pragma unroll
            for (int e = 0; e < NEXP; ++e)
                bv[ni][e] = (ng < NREAL) ? bias[(size_t)e * NREAL + ng] : 0.f;
        }
        #pragma unroll
        for (int mi = 0; mi < 4; ++mi) {
            f32x4 wve[NEXP];
            #pragma unroll
            for (int e = 0; e < NEXP; ++e)
                wve[e] = *(const f32x4*)&wlsT[e][wr * 64 + mi * 16 + l4 * 4];
            #pragma unroll
            for (int ni = 0; ni < 4; ++ni)
                #pragma unroll
                for (int j = 0; j < 4; ++j) {
                    float sum = 0.f;
                    #pragma unroll
                    for (int e = 0; e < NEXP; ++e) sum += wve[e][j] * bv[ni][e];
                    accF[mi][ni][j] += sum;
                }
        }
    }

    // store
    #pragma unroll
    for (int mi = 0; mi < 4; ++mi) {
        #pragma unroll
        for (int j = 0; j < 4; ++j) {
            size_t rg = (size_t)(m0 + wr * 64 + mi * 16 + l4 * 4 + j);
            #pragma unroll
            for (int ni = 0; ni < 4; ++ni) {
                int ng = n0 + wc * 64 + ni * 16 + lr;
                float v = accF[mi][ni][j];
                if (MODE == 0) {
                    v = v > 0.f ? v : expf(v) - 1.f;
                    ((short*)Out)[rg * NPAD + ng] = f2bf(v);
                } else {
                    if (ng < NREAL)
                        ((float*)Out)[rg * NREAL + ng] = v * Ynorm[NREAL + ng] + Ynorm[ng];
                }
            }
        }
    }
}

// ---------------------------------------------------------------------------
extern "C" void kernel_launch(void* const* d_in, const int* in_sizes, int n_in,
                              void* d_out, int out_size, void* d_ws, size_t ws_size,
                              hipStream_t stream) {
    const float* x     = (const float*)d_in[0];
    const float* Xnorm = (const float*)d_in[1];
    const float* Ynorm = (const float*)d_in[2];
    const float* G1W   = (const float*)d_in[3];
    const float* G1b   = (const float*)d_in[4];
    const float* G2W   = (const float*)d_in[5];
    const float* G2b   = (const float*)d_in[6];
    const float* G3W   = (const float*)d_in[7];
    const float* G3b   = (const float*)d_in[8];
    const float* W1    = (const float*)d_in[9];
    const float* b1    = (const float*)d_in[10];
    const float* W2    = (const float*)d_in[11];
    const float* b2    = (const float*)d_in[12];
    const float* W3    = (const float*)d_in[13];
    const float* b3    = (const float*)d_in[14];
    const int*   gidx  = (const int*)d_in[15];

    // workspace layout (m2 aliases xnbf: xnbf is fully consumed by layer 1)
    char* ws = (char*)d_ws;
    size_t off = 0;
    short* xnbf = (short*)(ws + off); off += (size_t)BATCH * KP * 2;        // 16.8 MB
    short* m1   = (short*)(ws + off); off += (size_t)BATCH * DH * 2;        // 16.8 MB
    short* Wt1  = (short*)(ws + off); off += (size_t)NEXP * DH  * KP * 2;   // 4.2 MB
    short* Wt2  = (short*)(ws + off); off += (size_t)NEXP * DH  * KP * 2;   // 4.2 MB
    short* Wt3  = (short*)(ws + off); off += (size_t)NEXP * 384 * KP * 2;   // 3.1 MB
    float* wg   = (float*)(ws + off); off += (size_t)BATCH * NEXP * 4;      // 0.5 MB
    short* m2   = xnbf;
    if (off > ws_size) return;

    // 1. normalize x -> bf16 (pitch 512, zero-padded)
    prep_xn_kernel<<<BATCH * 64 / 256, 256, 0, stream>>>(x, Xnorm, xnbf);

    // 2. transpose weights to [E][NPAD][KP] bf16 (K zero-padded)
    transpose_w_kernel<<<NEXP * (KP / 32) * (DH / 32), 256, 0, stream>>>(W1, Wt1, DIN, DH, DH);
    transpose_w_kernel<<<NEXP * (KP / 32) * (DH / 32), 256, 0, stream>>>(W2, Wt2, DH, DH, DH);
    transpose_w_kernel<<<NEXP * (KP / 32) * (384 / 32), 256, 0, stream>>>(W3, Wt3, DH, DOUT, 384);

    // 3. gating -> w[B][8]
    gating_kernel<<<256, 256, 0, stream>>>(x, Xnorm, G1W, G1b, G2W, G2b, G3W, G3b, gidx, wg);

    // 4. expert layers (BM=256, BN=128)
    expert_v14_kernel<DH, DH, 0>
        <<<(BATCH / 256) * (DH / 128), 512, 0, stream>>>(xnbf, Wt1, wg, b1, Ynorm, m1);
    expert_v14_kernel<DH, DH, 0>
        <<<(BATCH / 256) * (DH / 128), 512, 0, stream>>>(m1, Wt2, wg, b2, Ynorm, m2);
    expert_v14_kernel<384, DOUT, 1>
        <<<(BATCH / 256) * (384 / 128), 512, 0, stream>>>(m2, Wt3, wg, b3, Ynorm, (void*)d_out);
}